// Round 16
// baseline (34.832 us; speedup 1.0000x reference)
//
#include <hip/hip_runtime.h>
#include <hip/hip_bf16.h>
#include <math.h>

#define BB 2
#define CC 32
#define C8 4
#define NN 4096
#define VST 72        // LDS V tile row stride in shorts (R12-proven)
#define LOG2E 1.4426950408889634f

typedef __attribute__((ext_vector_type(8))) short short8;
typedef __attribute__((ext_vector_type(4))) float f32x4;
typedef __attribute__((ext_vector_type(16))) float f32x16;

static __device__ __forceinline__ short f2bf(float x) {
    return __builtin_bit_cast(short, __float2bfloat16(x));
}
static __device__ __forceinline__ unsigned int pkbf(float a, float b) {
    unsigned int ua = __builtin_bit_cast(unsigned int, a) + 0x8000u;
    unsigned int ub = __builtin_bit_cast(unsigned int, b) + 0x8000u;
    return (ua >> 16) | (ub & 0xffff0000u);
}
static __device__ __forceinline__ short f2bfr(float a) {
    return (short)((__builtin_bit_cast(unsigned int, a) + 0x8000u) >> 16);
}

// ---------------- K1: QKV projection (blocks 0..63) + CAM gram c<=d (blocks 64..327) ----
__global__ __launch_bounds__(256) void k1(const float* __restrict__ x,
    const float* __restrict__ wq, const float* __restrict__ bq,
    const float* __restrict__ wk, const float* __restrict__ bk,
    const float* __restrict__ wv, const float* __restrict__ bv,
    short* __restrict__ qpk, short* __restrict__ kpk, short* __restrict__ vbf,
    float* __restrict__ eng)
{
    if (blockIdx.x >= 64) {
        int w = threadIdx.x >> 6, lane = threadIdx.x & 63;
        int pp = (blockIdx.x - 64)*4 + w;     // 0..1055
        int b = pp >= 528 ? 1 : 0;
        int t = pp - b*528;
        int c = 0, rem = t;
        while (rem >= CC - c) { rem -= CC - c; ++c; }
        int d = c + rem;
        const float4* xc = (const float4*)(x + ((size_t)b*CC + c)*NN);
        const float4* xd = (const float4*)(x + ((size_t)b*CC + d)*NN);
        float s = 0.f;
        for (int tt = lane; tt < NN/4; tt += 64) {
            float4 a = xc[tt], bb = xd[tt];
            s += a.x*bb.x + a.y*bb.y + a.z*bb.z + a.w*bb.w;
        }
        #pragma unroll
        for (int off = 32; off; off >>= 1) s += __shfl_down(s, off, 64);
        if (lane == 0) {
            eng[(b*CC + c)*CC + d] = s;
            eng[(b*CC + d)*CC + c] = s;
        }
        return;
    }
    __shared__ float swq[C8*CC], swk[C8*CC], swv[CC*CC], sbq[C8], sbk[C8], sbv[CC];
    int tid = threadIdx.x;
    for (int i = tid; i < C8*CC; i += 256) { swq[i] = wq[i]; swk[i] = wk[i]; }
    for (int i = tid; i < CC*CC; i += 256) swv[i] = wv[i];
    if (tid < C8) { sbq[tid] = bq[tid]; sbk[tid] = bk[tid]; }
    if (tid < CC) sbv[tid] = bv[tid];
    __syncthreads();
    int tl = tid & 127, oh = tid >> 7;
    int g = blockIdx.x*128 + tl;          // 0..8191
    int b = g >> 12; int n = g & (NN-1);
    const float* xb = x + (size_t)b*CC*NN + n;
    float xr[CC];
    #pragma unroll
    for (int c = 0; c < CC; ++c) xr[c] = xb[(size_t)c*NN];
    if (oh == 0) {
        float qv[C8], kv[C8];
        #pragma unroll
        for (int o = 0; o < C8; ++o) { qv[o] = sbq[o]; kv[o] = sbk[o]; }
        #pragma unroll
        for (int c = 0; c < CC; ++c) {
            float xc = xr[c];
            #pragma unroll
            for (int o = 0; o < C8; ++o) { qv[o] += swq[o*CC+c]*xc; kv[o] += swk[o*CC+c]*xc; }
        }
        short4 qs = make_short4(f2bf(qv[0]*LOG2E), f2bf(qv[1]*LOG2E),
                                f2bf(qv[2]*LOG2E), f2bf(qv[3]*LOG2E));
        short4 ks = make_short4(f2bf(kv[0]), f2bf(kv[1]), f2bf(kv[2]), f2bf(kv[3]));
        *(short4*)(qpk + ((size_t)b*NN + n)*4) = qs;
        *(short4*)(kpk + ((size_t)b*NN + n)*4) = ks;
    }
    int o0 = oh*16;
    #pragma unroll
    for (int o = 0; o < 16; ++o) {
        float av = sbv[o0+o];
        #pragma unroll
        for (int c = 0; c < CC; ++c) av += swv[(o0+o)*CC+c]*xr[c];
        vbf[((size_t)b*CC+o0+o)*NN + n] = f2bf(av);
    }
}

// ---------------- K2: fused flash (R12-identical loop) + MFMA-projection tail ----
__global__ __launch_bounds__(1024, 4) void k2(const short* __restrict__ qpk,
    const short* __restrict__ kpk, const short* __restrict__ vbf,
    const float* __restrict__ eng, const float* __restrict__ wo,
    const float* __restrict__ bo, const float* __restrict__ gp,
    const float* __restrict__ gc, const float* __restrict__ x,
    float* __restrict__ out)
{
    __shared__ __align__(16) char smem[99328];

    int blk = blockIdx.x;
    int b  = blk >> 7;
    int it = blk & 127;
    int i0 = it*32;
    int tid = threadIdx.x;
    int w = tid >> 6, lane = tid & 63;
    int qcol = lane & 31, h = lane >> 5;

    short* vbuf = (short*)smem + w*(32*VST);

    int rv = lane >> 1, ch = lane & 1;
    const short* vsrc = vbf + (size_t)b*CC*NN + (size_t)rv*NN + w*64 + ch*32;
    const short* ksrc = kpk + ((size_t)b*NN + w*64 + qcol)*4;

    short8 qf = {0,0,0,0,0,0,0,0};
    if (h == 0) {
        short4 qv = *(const short4*)(qpk + ((size_t)b*NN + i0 + qcol)*4);
        qf[0]=qv.x; qf[1]=qv.y; qf[2]=qv.z; qf[3]=qv.w;
    }

    f32x16 acc = {0,0,0,0,0,0,0,0,0,0,0,0,0,0,0,0};
    const f32x16 zz = {0,0,0,0,0,0,0,0,0,0,0,0,0,0,0,0};
    float se = 0.f;

    // V/K prefetch ring (R12)
    short8 cv0 = *(const short8*)(vsrc);
    short8 cv1 = *(const short8*)(vsrc + 8);
    short8 cv2 = *(const short8*)(vsrc + 16);
    short8 cv3 = *(const short8*)(vsrc + 24);
    short4 ck0 = *(const short4*)(ksrc);
    short4 ck1 = *(const short4*)(ksrc + 128);

    #pragma unroll
    for (int t = 0; t < 4; ++t) {
        int tn = t < 3 ? t + 1 : 3;
        short8 nv0 = *(const short8*)(vsrc + tn*1024);
        short8 nv1 = *(const short8*)(vsrc + tn*1024 + 8);
        short8 nv2 = *(const short8*)(vsrc + tn*1024 + 16);
        short8 nv3 = *(const short8*)(vsrc + tn*1024 + 24);
        short4 nk0 = *(const short4*)(ksrc + tn*4096);
        short4 nk1 = *(const short4*)(ksrc + tn*4096 + 128);

        short* wp = vbuf + rv*VST + ch*32;
        *(short8*)(wp)      = cv0;
        *(short8*)(wp + 8)  = cv1;
        *(short8*)(wp + 16) = cv2;
        *(short8*)(wp + 24) = cv3;

        const short* vrow = vbuf + qcol*VST;
        #pragma unroll
        for (int cI = 0; cI < 2; ++cI) {
            short8 kf = {0,0,0,0,0,0,0,0};
            if (h == 0) {
                short4 kk = cI ? ck1 : ck0;
                kf[0]=kk.x; kf[1]=kk.y; kf[2]=kk.z; kf[3]=kk.w;
            }
            f32x16 s = __builtin_amdgcn_mfma_f32_32x32x16_bf16(kf, qf, zz, 0, 0, 0);
            unsigned int u[8];
            #pragma unroll
            for (int g4 = 0; g4 < 4; ++g4) {
                float p0 = exp2f(s[4*g4]),   p1 = exp2f(s[4*g4+1]);
                float p2 = exp2f(s[4*g4+2]), p3 = exp2f(s[4*g4+3]);
                se += (p0+p1)+(p2+p3);
                u[2*g4]   = pkbf(p0,p1);
                u[2*g4+1] = pkbf(p2,p3);
            }
            int vo = cI*32 + 4*h;
            short4 a0 = *(const short4*)(vrow + vo);
            short4 a1 = *(const short4*)(vrow + vo + 8);
            short4 a2 = *(const short4*)(vrow + vo + 16);
            short4 a3 = *(const short4*)(vrow + vo + 24);
            short8 vf1 = {a0.x,a0.y,a0.z,a0.w, a1.x,a1.y,a1.z,a1.w};
            short8 pf1 = {(short)u[0],(short)(u[0]>>16),(short)u[1],(short)(u[1]>>16),
                          (short)u[2],(short)(u[2]>>16),(short)u[3],(short)(u[3]>>16)};
            acc = __builtin_amdgcn_mfma_f32_32x32x16_bf16(vf1, pf1, acc, 0, 0, 0);
            short8 vf2 = {a2.x,a2.y,a2.z,a2.w, a3.x,a3.y,a3.z,a3.w};
            short8 pf2 = {(short)u[4],(short)(u[4]>>16),(short)u[5],(short)(u[5]>>16),
                          (short)u[6],(short)(u[6]>>16),(short)u[7],(short)(u[7]>>16)};
            acc = __builtin_amdgcn_mfma_f32_32x32x16_bf16(vf2, pf2, acc, 0, 0, 0);
        }
        cv0 = nv0; cv1 = nv1; cv2 = nv2; cv3 = nv3;
        ck0 = nk0; ck1 = nk1;
    }

    se += __shfl_xor(se, 32, 64);

    // ================= tail: vectorized combine + MFMA projection =================
    __syncthreads();
    float* smf  = (float*)smem;
    float* pamw = smf;               // [16][32][36]  (73728 B, aliases V bufs)
    float* seng = smf + 18432;       // [1024]
    float* sct  = seng + 1024;       // [32 d][36]  sc_t[d][c2] = cattn[c2][d]
    float* swo2 = sct  + 1152;       // [32 o][36]  wo second half
    float* seLt = swo2 + 1152;       // [32 q][16]
    float* sinv = seLt + 512;        // [32]
    float* sbo  = sinv + 32;         // [32]
    short* Zp   = (short*)(smf + 22336);   // [4 t][2 h][32 q][8 e] bf16 (4096 B)
    short* Wp   = Zp + 2048;               // [4 t][2 h][32 o][8 e] bf16 (4096 B)

    // ---- phase A: deposit flash results + stage small tables ----
    #pragma unroll
    for (int r = 0; r < 16; ++r) {
        int c = (r&3) + 8*(r>>2) + 4*h;
        pamw[w*1152 + qcol*36 + c] = acc[r];
    }
    if (h == 0) seLt[qcol*16 + w] = se;
    {
        int o = tid >> 5, c2 = tid & 31;
        seng[tid] = eng[b*CC*CC + tid];
        swo2[o*36 + c2] = wo[o*64 + 32 + c2];
        if (tid < CC) sbo[tid] = bo[tid];
    }
    __syncthreads();

    // ---- phase B: sumexp inverse + CAM row softmax ----
    if (tid < CC) {
        f32x4 a0 = *(f32x4*)(seLt + tid*16);
        f32x4 a1 = *(f32x4*)(seLt + tid*16 + 4);
        f32x4 a2 = *(f32x4*)(seLt + tid*16 + 8);
        f32x4 a3 = *(f32x4*)(seLt + tid*16 + 12);
        f32x4 t4 = (a0 + a1) + (a2 + a3);
        sinv[tid] = 1.f / ((t4[0]+t4[1]) + (t4[2]+t4[3]));
    } else if (tid >= 64 && tid < 64 + CC) {
        int r2 = tid - 64;     // CAM row c2 = r2
        float mn = seng[r2*32];
        #pragma unroll
        for (int d = 1; d < CC; ++d) mn = fminf(mn, seng[r2*32 + d]);
        float pv[CC]; float s = 0.f;
        #pragma unroll
        for (int d = 0; d < CC; ++d) { pv[d] = __expf(mn - seng[r2*32 + d]); s += pv[d]; }
        float inv = 1.f / s;
        #pragma unroll
        for (int d = 0; d < CC; ++d) sct[d*36 + r2] = pv[d]*inv;
    }
    __syncthreads();

    // ---- phase C: pack W (32x64) and Z (64x32) in MFMA fragment order ----
    // element mapping within a K=16 chunk: k=(e&3)+4h+8(e>>2); for c=4cg+j:
    // t=..., hh=cg&1, e0=4*((cg>>1)&1), e=e0+j (contiguous) -> b64 writes.
    {
        int grp = tid >> 8;            // 0..3
        int j   = tid & 255;
        int row = j >> 3;              // q (grp 0,1) or o (grp 2,3)
        int cg  = j & 7;
        int hh  = cg & 1;
        int e0  = 4*((cg>>1)&1);
        if (grp == 0) {                // Z rows 0..31 : gp*sinv[q]*pam_sum
            f32x4 s4 = {0.f,0.f,0.f,0.f};
            #pragma unroll
            for (int w2 = 0; w2 < 16; ++w2)
                s4 += *(f32x4*)(pamw + w2*1152 + row*36 + cg*4);
            float scl = gp[0] * sinv[row];
            int t = cg >> 2;
            short4 zv = make_short4(f2bfr(s4[0]*scl), f2bfr(s4[1]*scl),
                                    f2bfr(s4[2]*scl), f2bfr(s4[3]*scl));
            *(short4*)(Zp + ((t*2 + hh)*32 + row)*8 + e0) = zv;
        } else if (grp == 1) {         // Z rows 32..63 : x tile
            int t = 2 + (cg >> 2);
            const float* xb2 = x + (size_t)b*CC*NN + i0 + row;
            short4 zv = make_short4(
                f2bfr(xb2[(size_t)(4*cg+0)*NN]), f2bfr(xb2[(size_t)(4*cg+1)*NN]),
                f2bfr(xb2[(size_t)(4*cg+2)*NN]), f2bfr(xb2[(size_t)(4*cg+3)*NN]));
            *(short4*)(Zp + ((t*2 + hh)*32 + row)*8 + e0) = zv;
        } else if (grp == 2) {         // W cols 0..31 : wo first half
            float4 wv = *(const float4*)(wo + row*64 + 4*cg);
            int t = cg >> 2;
            short4 wv4 = make_short4(f2bfr(wv.x), f2bfr(wv.y), f2bfr(wv.z), f2bfr(wv.w));
            *(short4*)(Wp + ((t*2 + hh)*32 + row)*8 + e0) = wv4;
        } else {                       // W cols 32..63 : folded CAM weight Wx
            float4 w1 = *(const float4*)(wo + row*64 + 4*cg);
            float4 w2 = *(const float4*)(wo + row*64 + 32 + 4*cg);
            float gcv = gc[0];
            float val[4];
            #pragma unroll
            for (int jj = 0; jj < 4; ++jj) {
                int d = 4*cg + jj;
                f32x4 acc4 = {0.f,0.f,0.f,0.f};
                #pragma unroll
                for (int kk = 0; kk < 8; ++kk)
                    acc4 += (*(f32x4*)(swo2 + row*36 + kk*4)) * (*(f32x4*)(sct + d*36 + kk*4));
                float t2 = (acc4[0]+acc4[1]) + (acc4[2]+acc4[3]);
                val[jj] = ((const float*)&w1)[jj] + ((const float*)&w2)[jj] + gcv * t2;
            }
            int t = 2 + (cg >> 2);
            short4 wv4 = make_short4(f2bfr(val[0]), f2bfr(val[1]), f2bfr(val[2]), f2bfr(val[3]));
            *(short4*)(Wp + ((t*2 + hh)*32 + row)*8 + e0) = wv4;
        }
    }
    __syncthreads();

    // ---- final: wave 0 projects via 4 MFMAs and stores ----
    if (tid < 64) {
        f32x16 dacc = {0,0,0,0,0,0,0,0,0,0,0,0,0,0,0,0};
        #pragma unroll
        for (int t = 0; t < 4; ++t) {
            short8 af = *(short8*)(Wp + ((t*2 + h)*32 + qcol)*8);
            short8 bf_ = *(short8*)(Zp + ((t*2 + h)*32 + qcol)*8);
            dacc = __builtin_amdgcn_mfma_f32_32x32x16_bf16(af, bf_, dacc, 0, 0, 0);
        }
        float* ob = out + (size_t)b*CC*NN + i0 + qcol;
        #pragma unroll
        for (int r = 0; r < 16; ++r) {
            int o = (r&3) + 8*(r>>2) + 4*h;
            ob[(size_t)o*NN] = dacc[r] + sbo[o];
        }
    }
}

extern "C" void kernel_launch(void* const* d_in, const int* in_sizes, int n_in,
                              void* d_out, int out_size, void* d_ws, size_t ws_size,
                              hipStream_t stream)
{
    const float* x  = (const float*)d_in[0];
    const float* wq = (const float*)d_in[1];
    const float* bq = (const float*)d_in[2];
    const float* wk = (const float*)d_in[3];
    const float* bk = (const float*)d_in[4];
    const float* wv = (const float*)d_in[5];
    const float* bv = (const float*)d_in[6];
    const float* gp = (const float*)d_in[7];
    const float* gc = (const float*)d_in[8];
    const float* wo = (const float*)d_in[9];
    const float* bo = (const float*)d_in[10];

    char* wsb = (char*)d_ws;
    short* qpk = (short*)(wsb + 0);          // 65536 B
    short* kpk = (short*)(wsb + 65536);      // 65536 B
    short* vbf = (short*)(wsb + 131072);     // 524288 B
    float* eng = (float*)(wsb + 655360);     // 8192 B

    k1<<<328, 256, 0, stream>>>(x, wq, bq, wk, bk, wv, bv, qpk, kpk, vbf, eng);
    k2<<<BB*128, 1024, 0, stream>>>(qpk, kpk, vbf, eng, wo, bo, gp, gc, x, (float*)d_out);
}